// Round 2
// baseline (192.881 us; speedup 1.0000x reference)
//
#include <hip/hip_runtime.h>
#include <hip/hip_bf16.h>
#include <stdint.h>

typedef __bf16 bf16x8 __attribute__((ext_vector_type(8)));
typedef float  f32x4  __attribute__((ext_vector_type(4)));

__device__ __forceinline__ unsigned short f2bf(float f) {
    union { float f; unsigned u; } v; v.f = f;
    unsigned r = v.u + 0x7fffu + ((v.u >> 16) & 1u);   // RNE
    return (unsigned short)(r >> 16);
}
__device__ __forceinline__ float bf2f(unsigned short u) {
    union { unsigned u; float f; } v; v.u = (unsigned)u << 16; return v.f;
}

// async global->LDS, 16B per lane, wave-uniform LDS base (+lane*16 in HW)
__device__ __forceinline__ void async16(void* lds, const void* g) {
    __builtin_amdgcn_global_load_lds(
        (const __attribute__((address_space(1))) unsigned int*)g,
        (__attribute__((address_space(3))) unsigned int*)lds, 16, 0, 0);
}

// Level geometry (bc=4 fixed):
//   N-offsets: L0 @0 (4*4096), L1 @16384 (4*1024), L2 @20480 (4*256); NT=21504
#define NT_ALL   21504
#define OFF_L1   16384
#define OFF_L2   20480

// ---------------- weight fp32 -> bf16 ([3z][3lvl][512][256] stays) ----------
__global__ __launch_bounds__(256) void convert_w_kernel(
    const float* __restrict__ wq, const float* __restrict__ wk,
    const float* __restrict__ wv, unsigned short* __restrict__ wb)
{
    const int n = 3 * 512 * 256;
    int t = blockIdx.z;
    const float* src = (t == 0) ? wq : (t == 1) ? wk : wv;
    int i = blockIdx.x * 256 + threadIdx.x;
    if (i < n) wb[(size_t)t * n + i] = f2bf(src[i]);
}

// ---------------- x [b][256][HW] f32 (3 levels) -> xT [NT_ALL][256] bf16 ----
__global__ __launch_bounds__(256) void transpose_kernel(
    const float* __restrict__ x0, const float* __restrict__ x1,
    const float* __restrict__ x2, unsigned short* __restrict__ xT)
{
    __shared__ unsigned short tile[64][65];
    int xb = blockIdx.x;                 // 0..83 (64 + 16 + 4 tiles of 64 hw)
    const float* xp; int tb, HW, lvl_off;
    if (xb < 64)      { xp = x0; tb = xb;      HW = 4096; lvl_off = 0;      }
    else if (xb < 80) { xp = x1; tb = xb - 64; HW = 1024; lvl_off = OFF_L1; }
    else              { xp = x2; tb = xb - 80; HW = 256;  lvl_off = OFF_L2; }
    int hw0 = tb * 64;
    int c0  = blockIdx.y * 64;
    int b   = blockIdx.z;
    xp += (size_t)b * 256 * HW;
    int tx = threadIdx.x & 63;
    int ty = threadIdx.x >> 6;                     // 0..3
#pragma unroll
    for (int i = 0; i < 16; ++i) {
        int c = c0 + ty * 16 + i;
        tile[ty * 16 + i][tx] = f2bf(xp[(size_t)c * HW + hw0 + tx]);
    }
    __syncthreads();
    unsigned short* op = xT + ((size_t)lvl_off + (size_t)b * HW + hw0) * 256 + c0;
#pragma unroll
    for (int i = 0; i < 16; ++i) {
        int r = ty * 16 + i;                       // local hw row
        op[(size_t)r * 256 + tx] = tile[tx][r];
    }
}

// ---------------- QKV GEMM: qkv[z][o][n] = W[z,lvl(n)][o]·xT[n] + bias ------
// M=512, K=256, N=NT_ALL. 128x128 tile, BK=32, 4 waves, 2-phase double-buffer.
__global__ __launch_bounds__(256) void qkv_gemm_kernel(
    const unsigned short* __restrict__ wb,       // [3z][3lvl][512][256]
    const float* __restrict__ bq, const float* __restrict__ bk,
    const float* __restrict__ bv,                // each [3][512]
    const unsigned short* __restrict__ xT,       // [NT][256]
    unsigned short* __restrict__ qkv)            // [3z][512][NT]
{
    int z   = blockIdx.z;
    int bn0 = blockIdx.x * 128;
    int bm0 = blockIdx.y * 128;
    int lvl = (bn0 >= OFF_L2) ? 2 : (bn0 >= OFF_L1) ? 1 : 0;
    const unsigned short* Wm = wb + ((size_t)z * 3 + lvl) * 131072;
    const float* bias = ((z == 0) ? bq : (z == 1) ? bk : bv) + lvl * 512;
    unsigned short* out = qkv + (size_t)z * 512 * NT_ALL;

    __shared__ unsigned short smem[2][8192];     // per buf: A 4096, B 4096

    int tid  = threadIdx.x;
    int lane = tid & 63;
    int wid  = tid >> 6;                    // 0..3
    int wr   = wid >> 1, wc = wid & 1;
    int l15  = lane & 15;
    int kg   = lane >> 4;                   // 0..3

    f32x4 acc[4][4];
#pragma unroll
    for (int i = 0; i < 4; ++i)
#pragma unroll
        for (int j = 0; j < 4; ++j) acc[i][j] = (f32x4){0.f, 0.f, 0.f, 0.f};

    // staging rows for this lane (fragment order: slot = (mt*64+lane)*16B)
    int aRow0 = bm0 + (2 * wid)     * 16 + l15;
    int aRow1 = bm0 + (2 * wid + 1) * 16 + l15;
    int bRow0 = bn0 + (2 * wid)     * 16 + l15;
    int bRow1 = bn0 + (2 * wid + 1) * 16 + l15;
    int kbase = kg * 8;

    // prologue: stage k-tile 0 into buf 0
    {
        unsigned short* As = smem[0];
        unsigned short* Bs = smem[0] + 4096;
        async16(As + (2 * wid)     * 512, Wm + (size_t)aRow0 * 256 + kbase);
        async16(As + (2 * wid + 1) * 512, Wm + (size_t)aRow1 * 256 + kbase);
        async16(Bs + (2 * wid)     * 512, xT + (size_t)bRow0 * 256 + kbase);
        async16(Bs + (2 * wid + 1) * 512, xT + (size_t)bRow1 * 256 + kbase);
    }
    __syncthreads();

    for (int it = 0; it < 8; ++it) {
        if (it < 7) {                        // stage NEXT k-tile into other buf
            int kk = (it + 1) * 32 + kbase;
            unsigned short* As = smem[(it + 1) & 1];
            unsigned short* Bs = As + 4096;
            async16(As + (2 * wid)     * 512, Wm + (size_t)aRow0 * 256 + kk);
            async16(As + (2 * wid + 1) * 512, Wm + (size_t)aRow1 * 256 + kk);
            async16(Bs + (2 * wid)     * 512, xT + (size_t)bRow0 * 256 + kk);
            async16(Bs + (2 * wid + 1) * 512, xT + (size_t)bRow1 * 256 + kk);
        }
        const unsigned short* As = smem[it & 1];
        const unsigned short* Bs = As + 4096;
        bf16x8 af[4], bg[4];
#pragma unroll
        for (int mi = 0; mi < 4; ++mi)
            af[mi] = *reinterpret_cast<const bf16x8*>(As + ((wr * 4 + mi) * 64 + lane) * 8);
#pragma unroll
        for (int ni = 0; ni < 4; ++ni)
            bg[ni] = *reinterpret_cast<const bf16x8*>(Bs + ((wc * 4 + ni) * 64 + lane) * 8);
#pragma unroll
        for (int mi = 0; mi < 4; ++mi)
#pragma unroll
            for (int ni = 0; ni < 4; ++ni)
                acc[mi][ni] = __builtin_amdgcn_mfma_f32_16x16x32_bf16(
                    af[mi], bg[ni], acc[mi][ni], 0, 0, 0);
        __syncthreads();   // drains vmcnt (next-tile loads had compute to land) + lgkm
    }

#pragma unroll
    for (int mi = 0; mi < 4; ++mi) {
        int obase = bm0 + wr * 64 + mi * 16 + kg * 4;
#pragma unroll
        for (int ni = 0; ni < 4; ++ni) {
            int n = bn0 + wc * 64 + ni * 16 + l15;
#pragma unroll
            for (int r = 0; r < 4; ++r) {
                int o = obase + r;
                out[(size_t)o * NT_ALL + n] = f2bf(acc[mi][ni][r] + bias[o]);
            }
        }
    }
}

// ---------------- 3x3 local attention + relu + spatial-mean accumulation ----
__global__ __launch_bounds__(256) void attn_kernel(
    const unsigned short* __restrict__ qkv,      // [3z][512][NT]
    const float* __restrict__ bk, const float* __restrict__ bv,   // [3][512]
    const float* __restrict__ relh, const float* __restrict__ relw,// [3][256][3]
    float* __restrict__ feat)
{
    int xb = blockIdx.x;                 // 0..20 (16 + 4 + 1 blocks of 256 hw)
    int c  = blockIdx.y;
    int b  = blockIdx.z;
    int tb, H, lgW, lvl_off, lvl;
    if (xb < 16)      { lvl = 0; tb = xb;      H = 64; lgW = 6; lvl_off = 0;      }
    else if (xb < 20) { lvl = 1; tb = xb - 16; H = 32; lgW = 5; lvl_off = OFF_L1; }
    else              { lvl = 2; tb = xb - 20; H = 16; lgW = 4; lvl_off = OFF_L2; }
    int HW = H << lgW;                   // W == H
    int hw = tb * 256 + threadIdx.x;
    int h = hw >> lgW, w = hw & (H - 1);
    size_t nbase = (size_t)lvl_off + (size_t)b * HW;
    const unsigned short* qp = qkv + (size_t)c          * NT_ALL + nbase;
    const unsigned short* kp = qkv + ((size_t)512 + c)  * NT_ALL + nbase;
    const unsigned short* vp = qkv + ((size_t)1024 + c) * NT_ALL + nbase;

    float q   = bf2f(qp[hw]);
    float bkc = bk[lvl * 512 + c], bvc = bv[lvl * 512 + c];
    float r3[3];
    {
        const float* rs = (c < 256) ? (relh + lvl * 768 + c * 3)
                                    : (relw + lvl * 768 + (c - 256) * 3);
        r3[0] = rs[0]; r3[1] = rs[1]; r3[2] = rs[2];
    }
    bool ish = (c < 256);
    float s[9], vv[9];
    int t = 0;
#pragma unroll
    for (int dy = -1; dy <= 1; ++dy) {
        int y = h + dy;
        bool yin = (unsigned)y < (unsigned)H;
#pragma unroll
        for (int dx = -1; dx <= 1; ++dx) {
            int x = w + dx;
            bool in = yin && ((unsigned)x < (unsigned)H);
            float kkv, vt;
            if (in) { int off = (y << lgW) + x; kkv = bf2f(kp[off]); vt = bf2f(vp[off]); }
            else    { kkv = bkc; vt = bvc; }
            float rr = ish ? r3[dy + 1] : r3[dx + 1];
            s[t] = q * (kkv + rr);
            vv[t] = vt;
            ++t;
        }
    }
    float m = s[0];
#pragma unroll
    for (int i = 1; i < 9; ++i) m = fmaxf(m, s[i]);
    float num = 0.f, den = 0.f;
#pragma unroll
    for (int i = 0; i < 9; ++i) { float p = __expf(s[i] - m); num += p * vv[i]; den += p; }
    float y = fmaxf(num / den, 0.f) * (1.0f / HW);

#pragma unroll
    for (int off = 32; off; off >>= 1) y += __shfl_down(y, off, 64);
    __shared__ float red[4];
    int lane = threadIdx.x & 63, wvi = threadIdx.x >> 6;
    if (lane == 0) red[wvi] = y;
    __syncthreads();
    if (threadIdx.x == 0) {
        float sum = red[0] + red[1] + red[2] + red[3];
        atomicAdd(&feat[(size_t)b * 512 + c], sum);
    }
}

// ---------------- classifiers: one wave per output row ----------------------
__global__ __launch_bounds__(256) void logits_kernel(
    const float* __restrict__ feat,
    const float* __restrict__ ws, const float* __restrict__ bs,
    const float* __restrict__ wf, const float* __restrict__ bff,
    const float* __restrict__ wo, const float* __restrict__ bo,
    float* __restrict__ out)
{
    __shared__ float f[2048];
    for (int i = threadIdx.x; i < 2048; i += 256) f[i] = feat[i];
    __syncthreads();
    int lane = threadIdx.x & 63;
    int wid  = threadIdx.x >> 6;
    long long row = (long long)blockIdx.x * 4 + wid;
    const float* wm; float bias; size_t obase; int ostride;
    if (row < 64500) {
        wm = ws + (size_t)row * 512; bias = bs[row]; obase = (size_t)row; ostride = 64500;
    } else if (row < 64500 + 489) {
        long long r = row - 64500;
        wm = wf + (size_t)r * 512; bias = bff[r]; obase = 258000 + (size_t)r; ostride = 489;
    } else if (row < 64500 + 489 + 140) {
        long long r = row - 64989;
        wm = wo + (size_t)r * 512; bias = bo[r]; obase = 259956 + (size_t)r; ostride = 140;
    } else return;

    f32x4 w1 = *(const f32x4*)(wm + lane * 4);
    f32x4 w2 = *(const f32x4*)(wm + 256 + lane * 4);
    float accs[4];
#pragma unroll
    for (int b = 0; b < 4; ++b) {
        const float* fb = f + b * 512 + lane * 4;
        f32x4 f1 = *(const f32x4*)fb;
        f32x4 f2 = *(const f32x4*)(fb + 256);
        accs[b] = w1.x * f1.x + w1.y * f1.y + w1.z * f1.z + w1.w * f1.w
                + w2.x * f2.x + w2.y * f2.y + w2.z * f2.z + w2.w * f2.w;
    }
#pragma unroll
    for (int off = 32; off; off >>= 1)
#pragma unroll
        for (int b = 0; b < 4; ++b) accs[b] += __shfl_down(accs[b], off, 64);
    if (lane == 0)
#pragma unroll
        for (int b = 0; b < 4; ++b) out[obase + (size_t)b * ostride] = accs[b] + bias;
}

extern "C" void kernel_launch(void* const* d_in, const int* in_sizes, int n_in,
                              void* d_out, int out_size, void* d_ws, size_t ws_size,
                              hipStream_t stream)
{
    const float* x0  = (const float*)d_in[0];
    const float* x1  = (const float*)d_in[1];
    const float* x2  = (const float*)d_in[2];
    const float* wq  = (const float*)d_in[3];
    const float* bq  = (const float*)d_in[4];
    const float* wk  = (const float*)d_in[5];
    const float* bk  = (const float*)d_in[6];
    const float* wv  = (const float*)d_in[7];
    const float* bv  = (const float*)d_in[8];
    const float* relh = (const float*)d_in[9];
    const float* relw = (const float*)d_in[10];
    const float* ws  = (const float*)d_in[11];
    const float* bs  = (const float*)d_in[12];
    const float* wf  = (const float*)d_in[13];
    const float* bff = (const float*)d_in[14];
    const float* wo  = (const float*)d_in[15];
    const float* bo  = (const float*)d_in[16];
    float* out = (float*)d_out;

    char* wsb = (char*)d_ws;
    float* feat = (float*)wsb;                                   // 8 KB
    unsigned short* wb = (unsigned short*)(wsb + 8192);          // 2.36 MB
    unsigned short* xT = (unsigned short*)(wsb + 8192 + 2359296);          // 11 MB
    unsigned short* qkv = (unsigned short*)(wsb + 8192 + 2359296 + 11010048); // 66 MB

    hipMemsetAsync(feat, 0, 4 * 512 * sizeof(float), stream);
    convert_w_kernel<<<dim3(1536, 1, 3), 256, 0, stream>>>(wq, wk, wv, wb);
    transpose_kernel<<<dim3(84, 4, 4), 256, 0, stream>>>(x0, x1, x2, xT);
    qkv_gemm_kernel<<<dim3(NT_ALL / 128, 4, 3), 256, 0, stream>>>(
        wb, bq, bk, bv, xT, qkv);
    attn_kernel<<<dim3(21, 512, 4), 256, 0, stream>>>(
        qkv, bk, bv, relh, relw, feat);
    const int rows = 64500 + 489 + 140;
    logits_kernel<<<dim3((rows + 3) / 4), 256, 0, stream>>>(feat, ws, bs, wf, bff, wo, bo, out);
}

// Round 3
// 156.651 us; speedup vs baseline: 1.2313x; 1.2313x over previous
//
#include <hip/hip_runtime.h>
#include <hip/hip_bf16.h>
#include <stdint.h>

typedef __bf16 bf16x8 __attribute__((ext_vector_type(8)));
typedef float  f32x4  __attribute__((ext_vector_type(4)));
typedef unsigned short u16x8 __attribute__((ext_vector_type(8)));

__device__ __forceinline__ unsigned short f2bf(float f) {
    union { float f; unsigned u; } v; v.f = f;
    unsigned r = v.u + 0x7fffu + ((v.u >> 16) & 1u);   // RNE
    return (unsigned short)(r >> 16);
}
__device__ __forceinline__ float bf2f(unsigned short u) {
    union { unsigned u; float f; } v; v.u = (unsigned)u << 16; return v.f;
}

// async global->LDS, 16B per lane, wave-uniform LDS base (+lane*16 in HW)
__device__ __forceinline__ void async16(void* lds, const void* g) {
    __builtin_amdgcn_global_load_lds(
        (const __attribute__((address_space(1))) unsigned int*)g,
        (__attribute__((address_space(3))) unsigned int*)lds, 16, 0, 0);
}

// Level geometry (bc=4 fixed):
//   N-offsets: L0 @0 (4*4096), L1 @16384 (4*1024), L2 @20480 (4*256); NT=21504
#define NT_ALL   21504
#define OFF_L1   16384
#define OFF_L2   20480

// ---------------- weight fp32 -> bf16 ([3z][3lvl][512][256] stays) ----------
__global__ __launch_bounds__(256) void convert_w_kernel(
    const float* __restrict__ wq, const float* __restrict__ wk,
    const float* __restrict__ wv, unsigned short* __restrict__ wb)
{
    const int n = 3 * 512 * 256;
    int t = blockIdx.z;
    const float* src = (t == 0) ? wq : (t == 1) ? wk : wv;
    int i = blockIdx.x * 256 + threadIdx.x;
    if (i < n) wb[(size_t)t * n + i] = f2bf(src[i]);
}

// ---------------- x [b][256][HW] f32 (3 levels) -> xT [NT_ALL][256] bf16 ----
__global__ __launch_bounds__(256) void transpose_kernel(
    const float* __restrict__ x0, const float* __restrict__ x1,
    const float* __restrict__ x2, unsigned short* __restrict__ xT)
{
    __shared__ unsigned short tile[64][65];
    int xb = blockIdx.x;                 // 0..83 (64 + 16 + 4 tiles of 64 hw)
    const float* xp; int tb, HW, lvl_off;
    if (xb < 64)      { xp = x0; tb = xb;      HW = 4096; lvl_off = 0;      }
    else if (xb < 80) { xp = x1; tb = xb - 64; HW = 1024; lvl_off = OFF_L1; }
    else              { xp = x2; tb = xb - 80; HW = 256;  lvl_off = OFF_L2; }
    int hw0 = tb * 64;
    int c0  = blockIdx.y * 64;
    int b   = blockIdx.z;
    xp += (size_t)b * 256 * HW;
    int tx = threadIdx.x & 63;
    int ty = threadIdx.x >> 6;                     // 0..3
#pragma unroll
    for (int i = 0; i < 16; ++i) {
        int c = c0 + ty * 16 + i;
        tile[ty * 16 + i][tx] = f2bf(xp[(size_t)c * HW + hw0 + tx]);
    }
    __syncthreads();
    unsigned short* op = xT + ((size_t)lvl_off + (size_t)b * HW + hw0) * 256 + c0;
#pragma unroll
    for (int i = 0; i < 16; ++i) {
        int r = ty * 16 + i;                       // local hw row
        op[(size_t)r * 256 + tx] = tile[tx][r];
    }
}

// ---------------- QKV GEMM: qkv[z][o][n] = W[z,lvl(n)][o]·xT[n] + bias ------
// M=512, K=256, N=NT_ALL. 128x128 tile, BK=32, 4 waves, 2-phase double-buffer.
__global__ __launch_bounds__(256) void qkv_gemm_kernel(
    const unsigned short* __restrict__ wb,       // [3z][3lvl][512][256]
    const float* __restrict__ bq, const float* __restrict__ bk,
    const float* __restrict__ bv,                // each [3][512]
    const unsigned short* __restrict__ xT,       // [NT][256]
    unsigned short* __restrict__ qkv)            // [3z][512][NT]
{
    int z   = blockIdx.z;
    int bn0 = blockIdx.x * 128;
    int bm0 = blockIdx.y * 128;
    int lvl = (bn0 >= OFF_L2) ? 2 : (bn0 >= OFF_L1) ? 1 : 0;
    const unsigned short* Wm = wb + ((size_t)z * 3 + lvl) * 131072;
    const float* bias = ((z == 0) ? bq : (z == 1) ? bk : bv) + lvl * 512;
    unsigned short* out = qkv + (size_t)z * 512 * NT_ALL;

    __shared__ unsigned short smem[2][8192];     // per buf: A 4096, B 4096

    int tid  = threadIdx.x;
    int lane = tid & 63;
    int wid  = tid >> 6;                    // 0..3
    int wr   = wid >> 1, wc = wid & 1;
    int l15  = lane & 15;
    int kg   = lane >> 4;                   // 0..3

    f32x4 acc[4][4];
#pragma unroll
    for (int i = 0; i < 4; ++i)
#pragma unroll
        for (int j = 0; j < 4; ++j) acc[i][j] = (f32x4){0.f, 0.f, 0.f, 0.f};

    // staging rows for this lane (fragment order: slot = (mt*64+lane)*16B)
    int aRow0 = bm0 + (2 * wid)     * 16 + l15;
    int aRow1 = bm0 + (2 * wid + 1) * 16 + l15;
    int bRow0 = bn0 + (2 * wid)     * 16 + l15;
    int bRow1 = bn0 + (2 * wid + 1) * 16 + l15;
    int kbase = kg * 8;

    // prologue: stage k-tile 0 into buf 0
    {
        unsigned short* As = smem[0];
        unsigned short* Bs = smem[0] + 4096;
        async16(As + (2 * wid)     * 512, Wm + (size_t)aRow0 * 256 + kbase);
        async16(As + (2 * wid + 1) * 512, Wm + (size_t)aRow1 * 256 + kbase);
        async16(Bs + (2 * wid)     * 512, xT + (size_t)bRow0 * 256 + kbase);
        async16(Bs + (2 * wid + 1) * 512, xT + (size_t)bRow1 * 256 + kbase);
    }
    __syncthreads();

    for (int it = 0; it < 8; ++it) {
        if (it < 7) {                        // stage NEXT k-tile into other buf
            int kk = (it + 1) * 32 + kbase;
            unsigned short* As = smem[(it + 1) & 1];
            unsigned short* Bs = As + 4096;
            async16(As + (2 * wid)     * 512, Wm + (size_t)aRow0 * 256 + kk);
            async16(As + (2 * wid + 1) * 512, Wm + (size_t)aRow1 * 256 + kk);
            async16(Bs + (2 * wid)     * 512, xT + (size_t)bRow0 * 256 + kk);
            async16(Bs + (2 * wid + 1) * 512, xT + (size_t)bRow1 * 256 + kk);
        }
        const unsigned short* As = smem[it & 1];
        const unsigned short* Bs = As + 4096;
        bf16x8 af[4], bg[4];
#pragma unroll
        for (int mi = 0; mi < 4; ++mi)
            af[mi] = *reinterpret_cast<const bf16x8*>(As + ((wr * 4 + mi) * 64 + lane) * 8);
#pragma unroll
        for (int ni = 0; ni < 4; ++ni)
            bg[ni] = *reinterpret_cast<const bf16x8*>(Bs + ((wc * 4 + ni) * 64 + lane) * 8);
#pragma unroll
        for (int mi = 0; mi < 4; ++mi)
#pragma unroll
            for (int ni = 0; ni < 4; ++ni)
                acc[mi][ni] = __builtin_amdgcn_mfma_f32_16x16x32_bf16(
                    af[mi], bg[ni], acc[mi][ni], 0, 0, 0);
        __syncthreads();   // drains vmcnt (next-tile loads had compute to land) + lgkm
    }

#pragma unroll
    for (int mi = 0; mi < 4; ++mi) {
        int obase = bm0 + wr * 64 + mi * 16 + kg * 4;
#pragma unroll
        for (int ni = 0; ni < 4; ++ni) {
            int n = bn0 + wc * 64 + ni * 16 + l15;
#pragma unroll
            for (int r = 0; r < 4; ++r) {
                int o = obase + r;
                out[(size_t)o * NT_ALL + n] = f2bf(acc[mi][ni][r] + bias[o]);
            }
        }
    }
}

// ---------------- 3x3 local attention + relu + spatial-mean ----------------
// Vectorized: each thread owns 8 consecutive w positions of one row.
// Loads are u16x8 (16B); stencil taps come from register windows kf/vf[3][10].
__global__ __launch_bounds__(256) void attn_kernel(
    const unsigned short* __restrict__ qkv,      // [3z][512][NT]
    const float* __restrict__ bk, const float* __restrict__ bv,   // [3][512]
    const float* __restrict__ relh, const float* __restrict__ relw,// [3][256][3]
    float* __restrict__ feat)
{
    int xb = blockIdx.x;                 // 0..10: 8 L0 + 2 L1 + 1 L2(half)
    int c  = blockIdx.y;
    int lvl, lgW, lvl_off, hw_all;
    if (xb < 8)       { lvl = 0; lgW = 6; lvl_off = 0;      hw_all = xb * 2048 + threadIdx.x * 8; }
    else if (xb < 10) { lvl = 1; lgW = 5; lvl_off = OFF_L1; hw_all = (xb - 8) * 2048 + threadIdx.x * 8; }
    else              { lvl = 2; lgW = 4; lvl_off = OFF_L2; hw_all = threadIdx.x * 8; }
    int W = 1 << lgW, H = W, HW = W << lgW;
    bool active = hw_all < 4 * HW;       // only partial for L2 block
    int b  = hw_all >> (2 * lgW);
    int hw = hw_all & (HW - 1);
    int h = hw >> lgW, w0 = hw & (W - 1);

    size_t n0 = (size_t)lvl_off + hw_all;
    const unsigned short* qp = qkv + (size_t)c          * NT_ALL + n0;
    const unsigned short* kp = qkv + ((size_t)512 + c)  * NT_ALL + n0;
    const unsigned short* vp = qkv + ((size_t)1024 + c) * NT_ALL + n0;

    float bkc = bk[lvl * 512 + c], bvc = bv[lvl * 512 + c];
    bool ish = (c < 256);
    const float* rs = ish ? (relh + lvl * 768 + c * 3)
                          : (relw + lvl * 768 + (c - 256) * 3);
    float relt[3][3];
#pragma unroll
    for (int r = 0; r < 3; ++r)
#pragma unroll
        for (int dc = 0; dc < 3; ++dc)
            relt[r][dc] = ish ? rs[r] : rs[dc];

    float qf[8], kf[3][10], vf[3][10];
    float ysum = 0.f;
    if (active) {
        u16x8 qv = *(const u16x8*)qp;
#pragma unroll
        for (int j = 0; j < 8; ++j) qf[j] = bf2f(qv[j]);
#pragma unroll
        for (int r = 0; r < 3; ++r) {
            int y = h + r - 1;
            if ((unsigned)y < (unsigned)H) {
                int off = (r - 1) << lgW;     // dy*W
                u16x8 kv = *(const u16x8*)(kp + off);
                u16x8 vv = *(const u16x8*)(vp + off);
#pragma unroll
                for (int j = 0; j < 8; ++j) { kf[r][j + 1] = bf2f(kv[j]); vf[r][j + 1] = bf2f(vv[j]); }
                kf[r][0] = (w0 > 0)     ? bf2f(kp[off - 1]) : bkc;
                vf[r][0] = (w0 > 0)     ? bf2f(vp[off - 1]) : bvc;
                kf[r][9] = (w0 + 8 < W) ? bf2f(kp[off + 8]) : bkc;
                vf[r][9] = (w0 + 8 < W) ? bf2f(vp[off + 8]) : bvc;
            } else {
#pragma unroll
                for (int j = 0; j < 10; ++j) { kf[r][j] = bkc; vf[r][j] = bvc; }
            }
        }
#pragma unroll
        for (int j = 0; j < 8; ++j) {
            float qj = qf[j];
            float s[9];
#pragma unroll
            for (int r = 0; r < 3; ++r)
#pragma unroll
                for (int dc = 0; dc < 3; ++dc)
                    s[r * 3 + dc] = qj * (kf[r][j + dc] + relt[r][dc]);
            float m = fmaxf(fmaxf(fmaxf(fmaxf(s[0], s[1]), s[2]),
                                  fmaxf(fmaxf(s[3], s[4]), s[5])),
                            fmaxf(fmaxf(s[6], s[7]), s[8]));
            float num = 0.f, den = 0.f;
#pragma unroll
            for (int r = 0; r < 3; ++r)
#pragma unroll
                for (int dc = 0; dc < 3; ++dc) {
                    float p = __expf(s[r * 3 + dc] - m);
                    num += p * vf[r][j + dc];
                    den += p;
                }
            ysum += fmaxf(__fdividef(num, den), 0.f);
        }
        ysum *= (1.0f / HW);
    }
    // half-wave (32-lane) reduction: each half-wave covers 256 positions = one b
#pragma unroll
    for (int off = 16; off; off >>= 1) ysum += __shfl_down(ysum, off, 32);
    if (active && ((threadIdx.x & 31) == 0))
        atomicAdd(&feat[(size_t)b * 512 + c], ysum);
}

// ---------------- classifiers: one wave per output row ----------------------
__global__ __launch_bounds__(256) void logits_kernel(
    const float* __restrict__ feat,
    const float* __restrict__ ws, const float* __restrict__ bs,
    const float* __restrict__ wf, const float* __restrict__ bff,
    const float* __restrict__ wo, const float* __restrict__ bo,
    float* __restrict__ out)
{
    __shared__ float f[2048];
    for (int i = threadIdx.x; i < 2048; i += 256) f[i] = feat[i];
    __syncthreads();
    int lane = threadIdx.x & 63;
    int wid  = threadIdx.x >> 6;
    long long row = (long long)blockIdx.x * 4 + wid;
    const float* wm; float bias; size_t obase; int ostride;
    if (row < 64500) {
        wm = ws + (size_t)row * 512; bias = bs[row]; obase = (size_t)row; ostride = 64500;
    } else if (row < 64500 + 489) {
        long long r = row - 64500;
        wm = wf + (size_t)r * 512; bias = bff[r]; obase = 258000 + (size_t)r; ostride = 489;
    } else if (row < 64500 + 489 + 140) {
        long long r = row - 64989;
        wm = wo + (size_t)r * 512; bias = bo[r]; obase = 259956 + (size_t)r; ostride = 140;
    } else return;

    f32x4 w1 = *(const f32x4*)(wm + lane * 4);
    f32x4 w2 = *(const f32x4*)(wm + 256 + lane * 4);
    float accs[4];
#pragma unroll
    for (int b = 0; b < 4; ++b) {
        const float* fb = f + b * 512 + lane * 4;
        f32x4 f1 = *(const f32x4*)fb;
        f32x4 f2 = *(const f32x4*)(fb + 256);
        accs[b] = w1.x * f1.x + w1.y * f1.y + w1.z * f1.z + w1.w * f1.w
                + w2.x * f2.x + w2.y * f2.y + w2.z * f2.z + w2.w * f2.w;
    }
#pragma unroll
    for (int off = 32; off; off >>= 1)
#pragma unroll
        for (int b = 0; b < 4; ++b) accs[b] += __shfl_down(accs[b], off, 64);
    if (lane == 0)
#pragma unroll
        for (int b = 0; b < 4; ++b) out[obase + (size_t)b * ostride] = accs[b] + bias;
}

extern "C" void kernel_launch(void* const* d_in, const int* in_sizes, int n_in,
                              void* d_out, int out_size, void* d_ws, size_t ws_size,
                              hipStream_t stream)
{
    const float* x0  = (const float*)d_in[0];
    const float* x1  = (const float*)d_in[1];
    const float* x2  = (const float*)d_in[2];
    const float* wq  = (const float*)d_in[3];
    const float* bq  = (const float*)d_in[4];
    const float* wk  = (const float*)d_in[5];
    const float* bk  = (const float*)d_in[6];
    const float* wv  = (const float*)d_in[7];
    const float* bv  = (const float*)d_in[8];
    const float* relh = (const float*)d_in[9];
    const float* relw = (const float*)d_in[10];
    const float* ws  = (const float*)d_in[11];
    const float* bs  = (const float*)d_in[12];
    const float* wf  = (const float*)d_in[13];
    const float* bff = (const float*)d_in[14];
    const float* wo  = (const float*)d_in[15];
    const float* bo  = (const float*)d_in[16];
    float* out = (float*)d_out;

    char* wsb = (char*)d_ws;
    float* feat = (float*)wsb;                                   // 8 KB
    unsigned short* wb = (unsigned short*)(wsb + 8192);          // 2.36 MB
    unsigned short* xT = (unsigned short*)(wsb + 8192 + 2359296);          // 11 MB
    unsigned short* qkv = (unsigned short*)(wsb + 8192 + 2359296 + 11010048); // 66 MB

    hipMemsetAsync(feat, 0, 4 * 512 * sizeof(float), stream);
    convert_w_kernel<<<dim3(1536, 1, 3), 256, 0, stream>>>(wq, wk, wv, wb);
    transpose_kernel<<<dim3(84, 4, 4), 256, 0, stream>>>(x0, x1, x2, xT);
    qkv_gemm_kernel<<<dim3(NT_ALL / 128, 4, 3), 256, 0, stream>>>(
        wb, bq, bk, bv, xT, qkv);
    attn_kernel<<<dim3(11, 512, 1), 256, 0, stream>>>(
        qkv, bk, bv, relh, relw, feat);
    const int rows = 64500 + 489 + 140;
    logits_kernel<<<dim3((rows + 3) / 4), 256, 0, stream>>>(feat, ws, bs, wf, bff, wo, bo, out);
}

// Round 4
// 148.990 us; speedup vs baseline: 1.2946x; 1.0514x over previous
//
#include <hip/hip_runtime.h>
#include <hip/hip_bf16.h>
#include <stdint.h>

typedef __bf16 bf16x8 __attribute__((ext_vector_type(8)));
typedef float  f32x4  __attribute__((ext_vector_type(4)));
typedef unsigned short u16x8 __attribute__((ext_vector_type(8)));

__device__ __forceinline__ unsigned short f2bf(float f) {
    union { float f; unsigned u; } v; v.f = f;
    unsigned r = v.u + 0x7fffu + ((v.u >> 16) & 1u);   // RNE
    return (unsigned short)(r >> 16);
}
__device__ __forceinline__ float bf2f(unsigned short u) {
    union { unsigned u; float f; } v; v.u = (unsigned)u << 16; return v.f;
}

// async global->LDS, 16B per lane, wave-uniform LDS base (+lane*16 in HW)
__device__ __forceinline__ void async16(void* lds, const void* g) {
    __builtin_amdgcn_global_load_lds(
        (const __attribute__((address_space(1))) unsigned int*)g,
        (__attribute__((address_space(3))) unsigned int*)lds, 16, 0, 0);
}

// Level geometry (bc=4 fixed):
//   N-offsets: L0 @0 (4*4096), L1 @16384 (4*1024), L2 @20480 (4*256); NT=21504
#define NT_ALL   21504
#define OFF_L1   16384
#define OFF_L2   20480

// ---------------- fused prep: feat=0 | w fp32->bf16 | x -> xT bf16 ----------
// grid: 1 (memset) + 4608 (convert, 3 tensors) + 1344 (transpose 84x4x4)
__global__ __launch_bounds__(256) void prep_kernel(
    const float* __restrict__ x0, const float* __restrict__ x1,
    const float* __restrict__ x2,
    const float* __restrict__ wq, const float* __restrict__ wk,
    const float* __restrict__ wv,
    unsigned short* __restrict__ wb, unsigned short* __restrict__ xT,
    float* __restrict__ feat)
{
    __shared__ unsigned short tile[64][65];
    int bid = blockIdx.x;
    if (bid == 0) {
        for (int i = threadIdx.x; i < 2048; i += 256) feat[i] = 0.f;
        return;
    }
    bid -= 1;
    if (bid < 4608) {                        // weight convert
        int t = bid / 1536;
        int i = (bid % 1536) * 256 + threadIdx.x;
        const float* src = (t == 0) ? wq : (t == 1) ? wk : wv;
        wb[(size_t)t * 393216 + i] = f2bf(src[i]);
        return;
    }
    bid -= 4608;                             // transpose: 84 x 4 x 4
    int xb = bid % 84;
    int c0 = ((bid / 84) & 3) * 64;
    int b  = bid / 336;
    const float* xp; int tb, HW, lvl_off;
    if (xb < 64)      { xp = x0; tb = xb;      HW = 4096; lvl_off = 0;      }
    else if (xb < 80) { xp = x1; tb = xb - 64; HW = 1024; lvl_off = OFF_L1; }
    else              { xp = x2; tb = xb - 80; HW = 256;  lvl_off = OFF_L2; }
    int hw0 = tb * 64;
    xp += (size_t)b * 256 * HW;
    int tx = threadIdx.x & 63;
    int ty = threadIdx.x >> 6;               // 0..3
#pragma unroll
    for (int i = 0; i < 16; ++i) {
        int c = c0 + ty * 16 + i;
        tile[ty * 16 + i][tx] = f2bf(xp[(size_t)c * HW + hw0 + tx]);
    }
    __syncthreads();
    unsigned short* op = xT + ((size_t)lvl_off + (size_t)b * HW + hw0) * 256 + c0;
#pragma unroll
    for (int i = 0; i < 16; ++i) {
        int r = ty * 16 + i;                 // local hw row
        op[(size_t)r * 256 + tx] = tile[tx][r];
    }
}

// ---------------- QKV GEMM: qkv[z][o][n] = W[z,lvl(n)][o]·xT[n] + bias ------
// M=512, K=256, N=NT_ALL. 128x128 tile, BK=32, 4 waves, 2-phase double-buffer.
// Grid 1-D 2016 = 168 n-tiles x 12 (m,z); n-tile-major order + XCD swizzle so
// the 12 (m,z) blocks sharing one x-tile are schedule-adjacent and L2-local.
__global__ __launch_bounds__(256) void qkv_gemm_kernel(
    const unsigned short* __restrict__ wb,       // [3z][3lvl][512][256]
    const float* __restrict__ bq, const float* __restrict__ bk,
    const float* __restrict__ bv,                // each [3][512]
    const unsigned short* __restrict__ xT,       // [NT][256]
    unsigned short* __restrict__ qkv)            // [3z][512][NT]
{
    int bid = blockIdx.x;                        // 2016 = 8 * 252
    int swz = (bid & 7) * 252 + (bid >> 3);      // bijective XCD swizzle
    int nt  = swz / 12;                          // 0..167 n-tile
    int mz  = swz % 12;
    int z   = mz >> 2;
    int bm0 = (mz & 3) * 128;
    int bn0 = nt * 128;
    int lvl = (bn0 >= OFF_L2) ? 2 : (bn0 >= OFF_L1) ? 1 : 0;
    const unsigned short* Wm = wb + ((size_t)z * 3 + lvl) * 131072;
    const float* bias = ((z == 0) ? bq : (z == 1) ? bk : bv) + lvl * 512;
    unsigned short* out = qkv + (size_t)z * 512 * NT_ALL;

    __shared__ unsigned short smem[2][8192];     // per buf: A 4096, B 4096

    int tid  = threadIdx.x;
    int lane = tid & 63;
    int wid  = tid >> 6;                    // 0..3
    int wr   = wid >> 1, wc = wid & 1;
    int l15  = lane & 15;
    int kg   = lane >> 4;                   // 0..3

    f32x4 acc[4][4];
#pragma unroll
    for (int i = 0; i < 4; ++i)
#pragma unroll
        for (int j = 0; j < 4; ++j) acc[i][j] = (f32x4){0.f, 0.f, 0.f, 0.f};

    // staging rows for this lane (fragment order: slot = (mt*64+lane)*16B)
    int aRow0 = bm0 + (2 * wid)     * 16 + l15;
    int aRow1 = bm0 + (2 * wid + 1) * 16 + l15;
    int bRow0 = bn0 + (2 * wid)     * 16 + l15;
    int bRow1 = bn0 + (2 * wid + 1) * 16 + l15;
    int kbase = kg * 8;

    // prologue: stage k-tile 0 into buf 0
    {
        unsigned short* As = smem[0];
        unsigned short* Bs = smem[0] + 4096;
        async16(As + (2 * wid)     * 512, Wm + (size_t)aRow0 * 256 + kbase);
        async16(As + (2 * wid + 1) * 512, Wm + (size_t)aRow1 * 256 + kbase);
        async16(Bs + (2 * wid)     * 512, xT + (size_t)bRow0 * 256 + kbase);
        async16(Bs + (2 * wid + 1) * 512, xT + (size_t)bRow1 * 256 + kbase);
    }
    __syncthreads();

    for (int it = 0; it < 8; ++it) {
        if (it < 7) {                        // stage NEXT k-tile into other buf
            int kk = (it + 1) * 32 + kbase;
            unsigned short* As = smem[(it + 1) & 1];
            unsigned short* Bs = As + 4096;
            async16(As + (2 * wid)     * 512, Wm + (size_t)aRow0 * 256 + kk);
            async16(As + (2 * wid + 1) * 512, Wm + (size_t)aRow1 * 256 + kk);
            async16(Bs + (2 * wid)     * 512, xT + (size_t)bRow0 * 256 + kk);
            async16(Bs + (2 * wid + 1) * 512, xT + (size_t)bRow1 * 256 + kk);
        }
        const unsigned short* As = smem[it & 1];
        const unsigned short* Bs = As + 4096;
        bf16x8 af[4], bg[4];
#pragma unroll
        for (int mi = 0; mi < 4; ++mi)
            af[mi] = *reinterpret_cast<const bf16x8*>(As + ((wr * 4 + mi) * 64 + lane) * 8);
#pragma unroll
        for (int ni = 0; ni < 4; ++ni)
            bg[ni] = *reinterpret_cast<const bf16x8*>(Bs + ((wc * 4 + ni) * 64 + lane) * 8);
#pragma unroll
        for (int mi = 0; mi < 4; ++mi)
#pragma unroll
            for (int ni = 0; ni < 4; ++ni)
                acc[mi][ni] = __builtin_amdgcn_mfma_f32_16x16x32_bf16(
                    af[mi], bg[ni], acc[mi][ni], 0, 0, 0);
        __syncthreads();   // drains vmcnt (next-tile loads had compute to land) + lgkm
    }

#pragma unroll
    for (int mi = 0; mi < 4; ++mi) {
        int obase = bm0 + wr * 64 + mi * 16 + kg * 4;
#pragma unroll
        for (int ni = 0; ni < 4; ++ni) {
            int n = bn0 + wc * 64 + ni * 16 + l15;
#pragma unroll
            for (int r = 0; r < 4; ++r) {
                int o = obase + r;
                out[(size_t)o * NT_ALL + n] = f2bf(acc[mi][ni][r] + bias[o]);
            }
        }
    }
}

// ---------------- 3x3 local attention + relu + spatial-mean ----------------
// Vectorized: each thread owns 8 consecutive w positions of one row.
__global__ __launch_bounds__(256) void attn_kernel(
    const unsigned short* __restrict__ qkv,      // [3z][512][NT]
    const float* __restrict__ bk, const float* __restrict__ bv,   // [3][512]
    const float* __restrict__ relh, const float* __restrict__ relw,// [3][256][3]
    float* __restrict__ feat)
{
    int xb = blockIdx.x;                 // 0..10: 8 L0 + 2 L1 + 1 L2(half)
    int c  = blockIdx.y;
    int lvl, lgW, lvl_off, hw_all;
    if (xb < 8)       { lvl = 0; lgW = 6; lvl_off = 0;      hw_all = xb * 2048 + threadIdx.x * 8; }
    else if (xb < 10) { lvl = 1; lgW = 5; lvl_off = OFF_L1; hw_all = (xb - 8) * 2048 + threadIdx.x * 8; }
    else              { lvl = 2; lgW = 4; lvl_off = OFF_L2; hw_all = threadIdx.x * 8; }
    int W = 1 << lgW, H = W, HW = W << lgW;
    bool active = hw_all < 4 * HW;       // only partial for L2 block
    int b  = hw_all >> (2 * lgW);
    int hw = hw_all & (HW - 1);
    int h = hw >> lgW, w0 = hw & (W - 1);

    size_t n0 = (size_t)lvl_off + hw_all;
    const unsigned short* qp = qkv + (size_t)c          * NT_ALL + n0;
    const unsigned short* kp = qkv + ((size_t)512 + c)  * NT_ALL + n0;
    const unsigned short* vp = qkv + ((size_t)1024 + c) * NT_ALL + n0;

    float bkc = bk[lvl * 512 + c], bvc = bv[lvl * 512 + c];
    bool ish = (c < 256);
    const float* rs = ish ? (relh + lvl * 768 + c * 3)
                          : (relw + lvl * 768 + (c - 256) * 3);
    float relt[3][3];
#pragma unroll
    for (int r = 0; r < 3; ++r)
#pragma unroll
        for (int dc = 0; dc < 3; ++dc)
            relt[r][dc] = ish ? rs[r] : rs[dc];

    float qf[8], kf[3][10], vf[3][10];
    float ysum = 0.f;
    if (active) {
        u16x8 qv = *(const u16x8*)qp;
#pragma unroll
        for (int j = 0; j < 8; ++j) qf[j] = bf2f(qv[j]);
#pragma unroll
        for (int r = 0; r < 3; ++r) {
            int y = h + r - 1;
            if ((unsigned)y < (unsigned)H) {
                int off = (r - 1) << lgW;     // dy*W
                u16x8 kv = *(const u16x8*)(kp + off);
                u16x8 vv = *(const u16x8*)(vp + off);
#pragma unroll
                for (int j = 0; j < 8; ++j) { kf[r][j + 1] = bf2f(kv[j]); vf[r][j + 1] = bf2f(vv[j]); }
                kf[r][0] = (w0 > 0)     ? bf2f(kp[off - 1]) : bkc;
                vf[r][0] = (w0 > 0)     ? bf2f(vp[off - 1]) : bvc;
                kf[r][9] = (w0 + 8 < W) ? bf2f(kp[off + 8]) : bkc;
                vf[r][9] = (w0 + 8 < W) ? bf2f(vp[off + 8]) : bvc;
            } else {
#pragma unroll
                for (int j = 0; j < 10; ++j) { kf[r][j] = bkc; vf[r][j] = bvc; }
            }
        }
#pragma unroll
        for (int j = 0; j < 8; ++j) {
            float qj = qf[j];
            float s[9];
#pragma unroll
            for (int r = 0; r < 3; ++r)
#pragma unroll
                for (int dc = 0; dc < 3; ++dc)
                    s[r * 3 + dc] = qj * (kf[r][j + dc] + relt[r][dc]);
            float m = fmaxf(fmaxf(fmaxf(fmaxf(s[0], s[1]), s[2]),
                                  fmaxf(fmaxf(s[3], s[4]), s[5])),
                            fmaxf(fmaxf(s[6], s[7]), s[8]));
            float num = 0.f, den = 0.f;
#pragma unroll
            for (int r = 0; r < 3; ++r)
#pragma unroll
                for (int dc = 0; dc < 3; ++dc) {
                    float p = __expf(s[r * 3 + dc] - m);
                    num += p * vf[r][j + dc];
                    den += p;
                }
            ysum += fmaxf(__fdividef(num, den), 0.f);
        }
        ysum *= (1.0f / HW);
    }
    // half-wave (32-lane) reduction: each half-wave covers 256 positions = one b
#pragma unroll
    for (int off = 16; off; off >>= 1) ysum += __shfl_down(ysum, off, 32);
    if (active && ((threadIdx.x & 31) == 0))
        atomicAdd(&feat[(size_t)b * 512 + c], ysum);
}

// ---------------- classifiers: one wave per output row ----------------------
__global__ __launch_bounds__(256) void logits_kernel(
    const float* __restrict__ feat,
    const float* __restrict__ ws, const float* __restrict__ bs,
    const float* __restrict__ wf, const float* __restrict__ bff,
    const float* __restrict__ wo, const float* __restrict__ bo,
    float* __restrict__ out)
{
    __shared__ float f[2048];
    for (int i = threadIdx.x; i < 2048; i += 256) f[i] = feat[i];
    __syncthreads();
    int lane = threadIdx.x & 63;
    int wid  = threadIdx.x >> 6;
    long long row = (long long)blockIdx.x * 4 + wid;
    const float* wm; float bias; size_t obase; int ostride;
    if (row < 64500) {
        wm = ws + (size_t)row * 512; bias = bs[row]; obase = (size_t)row; ostride = 64500;
    } else if (row < 64500 + 489) {
        long long r = row - 64500;
        wm = wf + (size_t)r * 512; bias = bff[r]; obase = 258000 + (size_t)r; ostride = 489;
    } else if (row < 64500 + 489 + 140) {
        long long r = row - 64989;
        wm = wo + (size_t)r * 512; bias = bo[r]; obase = 259956 + (size_t)r; ostride = 140;
    } else return;

    f32x4 w1 = *(const f32x4*)(wm + lane * 4);
    f32x4 w2 = *(const f32x4*)(wm + 256 + lane * 4);
    float accs[4];
#pragma unroll
    for (int b = 0; b < 4; ++b) {
        const float* fb = f + b * 512 + lane * 4;
        f32x4 f1 = *(const f32x4*)fb;
        f32x4 f2 = *(const f32x4*)(fb + 256);
        accs[b] = w1.x * f1.x + w1.y * f1.y + w1.z * f1.z + w1.w * f1.w
                + w2.x * f2.x + w2.y * f2.y + w2.z * f2.z + w2.w * f2.w;
    }
#pragma unroll
    for (int off = 32; off; off >>= 1)
#pragma unroll
        for (int b = 0; b < 4; ++b) accs[b] += __shfl_down(accs[b], off, 64);
    if (lane == 0)
#pragma unroll
        for (int b = 0; b < 4; ++b) out[obase + (size_t)b * ostride] = accs[b] + bias;
}

extern "C" void kernel_launch(void* const* d_in, const int* in_sizes, int n_in,
                              void* d_out, int out_size, void* d_ws, size_t ws_size,
                              hipStream_t stream)
{
    const float* x0  = (const float*)d_in[0];
    const float* x1  = (const float*)d_in[1];
    const float* x2  = (const float*)d_in[2];
    const float* wq  = (const float*)d_in[3];
    const float* bq  = (const float*)d_in[4];
    const float* wk  = (const float*)d_in[5];
    const float* bk  = (const float*)d_in[6];
    const float* wv  = (const float*)d_in[7];
    const float* bv  = (const float*)d_in[8];
    const float* relh = (const float*)d_in[9];
    const float* relw = (const float*)d_in[10];
    const float* ws  = (const float*)d_in[11];
    const float* bs  = (const float*)d_in[12];
    const float* wf  = (const float*)d_in[13];
    const float* bff = (const float*)d_in[14];
    const float* wo  = (const float*)d_in[15];
    const float* bo  = (const float*)d_in[16];
    float* out = (float*)d_out;

    char* wsb = (char*)d_ws;
    float* feat = (float*)wsb;                                   // 8 KB
    unsigned short* wb = (unsigned short*)(wsb + 8192);          // 2.36 MB
    unsigned short* xT = (unsigned short*)(wsb + 8192 + 2359296);          // 11 MB
    unsigned short* qkv = (unsigned short*)(wsb + 8192 + 2359296 + 11010048); // 66 MB

    prep_kernel<<<dim3(1 + 4608 + 1344), 256, 0, stream>>>(
        x0, x1, x2, wq, wk, wv, wb, xT, feat);
    qkv_gemm_kernel<<<dim3(2016), 256, 0, stream>>>(
        wb, bq, bk, bv, xT, qkv);
    attn_kernel<<<dim3(11, 512, 1), 256, 0, stream>>>(
        qkv, bk, bv, relh, relw, feat);
    const int rows = 64500 + 489 + 140;
    logits_kernel<<<dim3((rows + 3) / 4), 256, 0, stream>>>(feat, ws, bs, wf, bff, wo, bo, out);
}

// Round 5
// 138.748 us; speedup vs baseline: 1.3902x; 1.0738x over previous
//
#include <hip/hip_runtime.h>
#include <hip/hip_bf16.h>
#include <stdint.h>

typedef __bf16 bf16x8 __attribute__((ext_vector_type(8)));
typedef float  f32x4  __attribute__((ext_vector_type(4)));
typedef unsigned short u16x8 __attribute__((ext_vector_type(8)));

__device__ __forceinline__ unsigned short f2bf(float f) {
    union { float f; unsigned u; } v; v.f = f;
    unsigned r = v.u + 0x7fffu + ((v.u >> 16) & 1u);   // RNE
    return (unsigned short)(r >> 16);
}
__device__ __forceinline__ float bf2f(unsigned short u) {
    union { unsigned u; float f; } v; v.u = (unsigned)u << 16; return v.f;
}

// async global->LDS, 16B per lane, wave-uniform LDS base (+lane*16 in HW)
__device__ __forceinline__ void async16(void* lds, const void* g) {
    __builtin_amdgcn_global_load_lds(
        (const __attribute__((address_space(1))) unsigned int*)g,
        (__attribute__((address_space(3))) unsigned int*)lds, 16, 0, 0);
}

// Level geometry (bc=4 fixed):
//   N-offsets: L0 @0 (4*4096), L1 @16384 (4*1024), L2 @20480 (4*256); NT=21504
#define NT_ALL   21504
#define OFF_L1   16384
#define OFF_L2   20480

// ---------------- fused prep: feat=0 | w fp32->bf16 | x -> xT bf16 ----------
__global__ __launch_bounds__(256) void prep_kernel(
    const float* __restrict__ x0, const float* __restrict__ x1,
    const float* __restrict__ x2,
    const float* __restrict__ wq, const float* __restrict__ wk,
    const float* __restrict__ wv,
    unsigned short* __restrict__ wb, unsigned short* __restrict__ xT,
    float* __restrict__ feat)
{
    __shared__ unsigned short tile[64][65];
    int bid = blockIdx.x;
    if (bid == 0) {
        for (int i = threadIdx.x; i < 2048; i += 256) feat[i] = 0.f;
        return;
    }
    bid -= 1;
    if (bid < 4608) {                        // weight convert
        int t = bid / 1536;
        int i = (bid % 1536) * 256 + threadIdx.x;
        const float* src = (t == 0) ? wq : (t == 1) ? wk : wv;
        wb[(size_t)t * 393216 + i] = f2bf(src[i]);
        return;
    }
    bid -= 4608;                             // transpose: 84 x 4 x 4
    int xb = bid % 84;
    int c0 = ((bid / 84) & 3) * 64;
    int b  = bid / 336;
    const float* xp; int tb, HW, lvl_off;
    if (xb < 64)      { xp = x0; tb = xb;      HW = 4096; lvl_off = 0;      }
    else if (xb < 80) { xp = x1; tb = xb - 64; HW = 1024; lvl_off = OFF_L1; }
    else              { xp = x2; tb = xb - 80; HW = 256;  lvl_off = OFF_L2; }
    int hw0 = tb * 64;
    xp += (size_t)b * 256 * HW;
    int tx = threadIdx.x & 63;
    int ty = threadIdx.x >> 6;               // 0..3
#pragma unroll
    for (int i = 0; i < 16; ++i) {
        int c = c0 + ty * 16 + i;
        tile[ty * 16 + i][tx] = f2bf(xp[(size_t)c * HW + hw0 + tx]);
    }
    __syncthreads();
    unsigned short* op = xT + ((size_t)lvl_off + (size_t)b * HW + hw0) * 256 + c0;
#pragma unroll
    for (int i = 0; i < 16; ++i) {
        int r = ty * 16 + i;                 // local hw row
        op[(size_t)r * 256 + tx] = tile[tx][r];
    }
}

// ---------------- QKV GEMM: qkv[z][o][n] = W[z,lvl(n)][o]·xT[n] + bias ------
// M=512, K=256, N=NT_ALL. 128x128 tile, BK=32, 4 waves.
// 3-buffer LDS, 2-tiles-ahead prefetch, counted vmcnt (never 0 mid-loop),
// raw s_barrier pairs (no full drain). XCD-swizzled 1-D grid.
__global__ __launch_bounds__(256) void qkv_gemm_kernel(
    const unsigned short* __restrict__ wb,       // [3z][3lvl][512][256]
    const float* __restrict__ bq, const float* __restrict__ bk,
    const float* __restrict__ bv,                // each [3][512]
    const unsigned short* __restrict__ xT,       // [NT][256]
    unsigned short* __restrict__ qkv)            // [3z][512][NT]
{
    int bid = blockIdx.x;                        // 2016 = 8 * 252
    int swz = (bid & 7) * 252 + (bid >> 3);      // bijective XCD swizzle
    int nt  = swz / 12;                          // 0..167 n-tile
    int mz  = swz % 12;
    int z   = mz >> 2;
    int bm0 = (mz & 3) * 128;
    int bn0 = nt * 128;
    int lvl = (bn0 >= OFF_L2) ? 2 : (bn0 >= OFF_L1) ? 1 : 0;
    const unsigned short* Wm = wb + ((size_t)z * 3 + lvl) * 131072;
    const float* bias = ((z == 0) ? bq : (z == 1) ? bk : bv) + lvl * 512;
    unsigned short* out = qkv + (size_t)z * 512 * NT_ALL;

    __shared__ unsigned short smem[3][8192];     // 3 bufs x (A 4096, B 4096)

    int tid  = threadIdx.x;
    int lane = tid & 63;
    int wid  = tid >> 6;                    // 0..3
    int wr   = wid >> 1, wc = wid & 1;
    int l15  = lane & 15;
    int kg   = lane >> 4;                   // 0..3

    f32x4 acc[4][4];
#pragma unroll
    for (int i = 0; i < 4; ++i)
#pragma unroll
        for (int j = 0; j < 4; ++j) acc[i][j] = (f32x4){0.f, 0.f, 0.f, 0.f};

    // staging rows for this lane (fragment order: slot = (mt*64+lane)*16B)
    int aRow0 = bm0 + (2 * wid)     * 16 + l15;
    int aRow1 = bm0 + (2 * wid + 1) * 16 + l15;
    int bRow0 = bn0 + (2 * wid)     * 16 + l15;
    int bRow1 = bn0 + (2 * wid + 1) * 16 + l15;
    int kbase = kg * 8;

    auto STAGE = [&](int t, int bufi) {
        int kk = t * 32 + kbase;
        unsigned short* As = smem[bufi];
        unsigned short* Bs = As + 4096;
        async16(As + (2 * wid)     * 512, Wm + (size_t)aRow0 * 256 + kk);
        async16(As + (2 * wid + 1) * 512, Wm + (size_t)aRow1 * 256 + kk);
        async16(Bs + (2 * wid)     * 512, xT + (size_t)bRow0 * 256 + kk);
        async16(Bs + (2 * wid + 1) * 512, xT + (size_t)bRow1 * 256 + kk);
    };

    STAGE(0, 0);
    STAGE(1, 1);
#pragma unroll
    for (int it = 0; it < 8; ++it) {
        if (it < 6) STAGE(it + 2, (it + 2) % 3);
        __builtin_amdgcn_sched_barrier(0);
        // wait own loads for tile `it`; leave later tiles in flight
        if (it < 6)       asm volatile("s_waitcnt vmcnt(8)" ::: "memory");
        else if (it == 6) asm volatile("s_waitcnt vmcnt(4)" ::: "memory");
        else              asm volatile("s_waitcnt vmcnt(0)" ::: "memory");
        __builtin_amdgcn_s_barrier();               // all waves' tile-it data in LDS
        __builtin_amdgcn_sched_barrier(0);          // keep ds_reads below
        const unsigned short* As = smem[it % 3];
        const unsigned short* Bs = As + 4096;
        bf16x8 af[4], bg[4];
#pragma unroll
        for (int mi = 0; mi < 4; ++mi)
            af[mi] = *reinterpret_cast<const bf16x8*>(As + ((wr * 4 + mi) * 64 + lane) * 8);
#pragma unroll
        for (int ni = 0; ni < 4; ++ni)
            bg[ni] = *reinterpret_cast<const bf16x8*>(Bs + ((wc * 4 + ni) * 64 + lane) * 8);
#pragma unroll
        for (int mi = 0; mi < 4; ++mi)
#pragma unroll
            for (int ni = 0; ni < 4; ++ni)
                acc[mi][ni] = __builtin_amdgcn_mfma_f32_16x16x32_bf16(
                    af[mi], bg[ni], acc[mi][ni], 0, 0, 0);
        asm volatile("s_waitcnt lgkmcnt(0)" ::: "memory");  // my ds_reads retired
        __builtin_amdgcn_s_barrier();               // safe to overwrite buf it
        __builtin_amdgcn_sched_barrier(0);          // keep next STAGE below
    }

#pragma unroll
    for (int mi = 0; mi < 4; ++mi) {
        int obase = bm0 + wr * 64 + mi * 16 + kg * 4;
#pragma unroll
        for (int ni = 0; ni < 4; ++ni) {
            int n = bn0 + wc * 64 + ni * 16 + l15;
#pragma unroll
            for (int r = 0; r < 4; ++r) {
                int o = obase + r;
                out[(size_t)o * NT_ALL + n] = f2bf(acc[mi][ni][r] + bias[o]);
            }
        }
    }
}

// ---------------- 3x3 local attention + relu + spatial-mean ----------------
// Per thread: 8 consecutive w positions. Lean math: no max-sub (|s|<~5 safe),
// log2e folded into q, rel_h pre-added into k row-window, rel_w as fma offset.
__global__ __launch_bounds__(256) void attn_kernel(
    const unsigned short* __restrict__ qkv,      // [3z][512][NT]
    const float* __restrict__ bk, const float* __restrict__ bv,   // [3][512]
    const float* __restrict__ relh, const float* __restrict__ relw,// [3][256][3]
    float* __restrict__ feat)
{
    int xb = blockIdx.x;                 // 0..10: 8 L0 + 2 L1 + 1 L2(half)
    int c  = blockIdx.y;
    int lvl, lgW, lvl_off, hw_all;
    if (xb < 8)       { lvl = 0; lgW = 6; lvl_off = 0;      hw_all = xb * 2048 + threadIdx.x * 8; }
    else if (xb < 10) { lvl = 1; lgW = 5; lvl_off = OFF_L1; hw_all = (xb - 8) * 2048 + threadIdx.x * 8; }
    else              { lvl = 2; lgW = 4; lvl_off = OFF_L2; hw_all = threadIdx.x * 8; }
    int W = 1 << lgW, H = W, HW = W << lgW;
    bool active = hw_all < 4 * HW;       // only partial for L2 block
    int b  = hw_all >> (2 * lgW);
    int hw = hw_all & (HW - 1);
    int h = hw >> lgW, w0 = hw & (W - 1);

    size_t n0 = (size_t)lvl_off + hw_all;
    const unsigned short* qp = qkv + (size_t)c          * NT_ALL + n0;
    const unsigned short* kp = qkv + ((size_t)512 + c)  * NT_ALL + n0;
    const unsigned short* vp = qkv + ((size_t)1024 + c) * NT_ALL + n0;

    float bkc = bk[lvl * 512 + c], bvc = bv[lvl * 512 + c];
    bool ish = (c < 256);
    const float* rs = ish ? (relh + lvl * 768 + c * 3)
                          : (relw + lvl * 768 + (c - 256) * 3);
    float radd[3], rdc[3];
#pragma unroll
    for (int r = 0; r < 3; ++r) {
        float rv = rs[r];
        radd[r] = ish ? rv : 0.f;        // pre-added per stencil row
        rdc[r]  = ish ? 0.f : rv;        // fma offset per stencil col
    }

    float ysum = 0.f;
    if (active) {
        float krow[3][10], vf[3][10];
        u16x8 qv = *(const u16x8*)qp;
#pragma unroll
        for (int r = 0; r < 3; ++r) {
            int y = h + r - 1;
            float ra = radd[r];
            if ((unsigned)y < (unsigned)H) {
                int off = (r - 1) << lgW;     // dy*W
                u16x8 kv = *(const u16x8*)(kp + off);
                u16x8 vv = *(const u16x8*)(vp + off);
#pragma unroll
                for (int j = 0; j < 8; ++j) {
                    krow[r][j + 1] = bf2f(kv[j]) + ra;
                    vf[r][j + 1]   = bf2f(vv[j]);
                }
                krow[r][0] = ((w0 > 0)     ? bf2f(kp[off - 1]) : bkc) + ra;
                vf[r][0]   =  (w0 > 0)     ? bf2f(vp[off - 1]) : bvc;
                krow[r][9] = ((w0 + 8 < W) ? bf2f(kp[off + 8]) : bkc) + ra;
                vf[r][9]   =  (w0 + 8 < W) ? bf2f(vp[off + 8]) : bvc;
            } else {
                float kpad = bkc + ra;
#pragma unroll
                for (int j = 0; j < 10; ++j) { krow[r][j] = kpad; vf[r][j] = bvc; }
            }
        }
#pragma unroll
        for (int j = 0; j < 8; ++j) {
            float qln = bf2f(qv[j]) * 1.4426950408889634f;   // q * log2(e)
            float pr0 = qln * rdc[0], pr1 = qln * rdc[1], pr2 = qln * rdc[2];
            float num = 0.f, den = 0.f;
#pragma unroll
            for (int r = 0; r < 3; ++r) {
                float p0 = exp2f(fmaf(qln, krow[r][j + 0], pr0));
                float p1 = exp2f(fmaf(qln, krow[r][j + 1], pr1));
                float p2 = exp2f(fmaf(qln, krow[r][j + 2], pr2));
                num = fmaf(p0, vf[r][j + 0], num);
                num = fmaf(p1, vf[r][j + 1], num);
                num = fmaf(p2, vf[r][j + 2], num);
                den += p0 + p1 + p2;
            }
            ysum += fmaxf(__fdividef(num, den), 0.f);
        }
        ysum *= (1.0f / HW);
    }
    // half-wave (32-lane) reduction: each half-wave covers 256 positions = one b
#pragma unroll
    for (int off = 16; off; off >>= 1) ysum += __shfl_down(ysum, off, 32);
    if (active && ((threadIdx.x & 31) == 0))
        atomicAdd(&feat[(size_t)b * 512 + c], ysum);
}

// ---------------- classifiers: grid-stride, one wave per output row ---------
__global__ __launch_bounds__(256) void logits_kernel(
    const float* __restrict__ feat,
    const float* __restrict__ ws, const float* __restrict__ bs,
    const float* __restrict__ wf, const float* __restrict__ bff,
    const float* __restrict__ wo, const float* __restrict__ bo,
    float* __restrict__ out)
{
    __shared__ float f[2048];
    for (int i = threadIdx.x; i < 2048; i += 256) f[i] = feat[i];
    __syncthreads();
    int lane = threadIdx.x & 63;
    int wid  = threadIdx.x >> 6;
    const int ROWS = 64500 + 489 + 140;
    for (int row = blockIdx.x * 4 + wid; row < ROWS; row += 8192) {
        const float* wm; float bias; size_t obase; int ostride;
        if (row < 64500) {
            wm = ws + (size_t)row * 512; bias = bs[row]; obase = (size_t)row; ostride = 64500;
        } else if (row < 64500 + 489) {
            int r = row - 64500;
            wm = wf + (size_t)r * 512; bias = bff[r]; obase = 258000 + (size_t)r; ostride = 489;
        } else {
            int r = row - 64989;
            wm = wo + (size_t)r * 512; bias = bo[r]; obase = 259956 + (size_t)r; ostride = 140;
        }
        f32x4 w1 = *(const f32x4*)(wm + lane * 4);
        f32x4 w2 = *(const f32x4*)(wm + 256 + lane * 4);
        float accs[4];
#pragma unroll
        for (int b = 0; b < 4; ++b) {
            const float* fb = f + b * 512 + lane * 4;
            f32x4 f1 = *(const f32x4*)fb;
            f32x4 f2 = *(const f32x4*)(fb + 256);
            accs[b] = w1.x * f1.x + w1.y * f1.y + w1.z * f1.z + w1.w * f1.w
                    + w2.x * f2.x + w2.y * f2.y + w2.z * f2.z + w2.w * f2.w;
        }
#pragma unroll
        for (int off = 32; off; off >>= 1)
#pragma unroll
            for (int b = 0; b < 4; ++b) accs[b] += __shfl_down(accs[b], off, 64);
        if (lane == 0)
#pragma unroll
            for (int b = 0; b < 4; ++b) out[obase + (size_t)b * ostride] = accs[b] + bias;
    }
}

extern "C" void kernel_launch(void* const* d_in, const int* in_sizes, int n_in,
                              void* d_out, int out_size, void* d_ws, size_t ws_size,
                              hipStream_t stream)
{
    const float* x0  = (const float*)d_in[0];
    const float* x1  = (const float*)d_in[1];
    const float* x2  = (const float*)d_in[2];
    const float* wq  = (const float*)d_in[3];
    const float* bq  = (const float*)d_in[4];
    const float* wk  = (const float*)d_in[5];
    const float* bk  = (const float*)d_in[6];
    const float* wv  = (const float*)d_in[7];
    const float* bv  = (const float*)d_in[8];
    const float* relh = (const float*)d_in[9];
    const float* relw = (const float*)d_in[10];
    const float* ws  = (const float*)d_in[11];
    const float* bs  = (const float*)d_in[12];
    const float* wf  = (const float*)d_in[13];
    const float* bff = (const float*)d_in[14];
    const float* wo  = (const float*)d_in[15];
    const float* bo  = (const float*)d_in[16];
    float* out = (float*)d_out;

    char* wsb = (char*)d_ws;
    float* feat = (float*)wsb;                                   // 8 KB
    unsigned short* wb = (unsigned short*)(wsb + 8192);          // 2.36 MB
    unsigned short* xT = (unsigned short*)(wsb + 8192 + 2359296);          // 11 MB
    unsigned short* qkv = (unsigned short*)(wsb + 8192 + 2359296 + 11010048); // 66 MB

    prep_kernel<<<dim3(1 + 4608 + 1344), 256, 0, stream>>>(
        x0, x1, x2, wq, wk, wv, wb, xT, feat);
    qkv_gemm_kernel<<<dim3(2016), 256, 0, stream>>>(
        wb, bq, bk, bv, xT, qkv);
    attn_kernel<<<dim3(11, 512, 1), 256, 0, stream>>>(
        qkv, bk, bv, relh, relw, feat);
    logits_kernel<<<dim3(2048), 256, 0, stream>>>(feat, ws, bs, wf, bff, wo, bo, out);
}

// Round 6
// 136.759 us; speedup vs baseline: 1.4104x; 1.0145x over previous
//
#include <hip/hip_runtime.h>
#include <hip/hip_bf16.h>
#include <stdint.h>

typedef __bf16 bf16x8 __attribute__((ext_vector_type(8)));
typedef float  f32x4  __attribute__((ext_vector_type(4)));
typedef unsigned short u16x8 __attribute__((ext_vector_type(8)));

__device__ __forceinline__ unsigned short f2bf(float f) {
    union { float f; unsigned u; } v; v.f = f;
    unsigned r = v.u + 0x7fffu + ((v.u >> 16) & 1u);   // RNE
    return (unsigned short)(r >> 16);
}
__device__ __forceinline__ float bf2f(unsigned short u) {
    union { unsigned u; float f; } v; v.u = (unsigned)u << 16; return v.f;
}

// async global->LDS, 16B per lane, wave-uniform LDS base (+lane*16 in HW)
__device__ __forceinline__ void async16(void* lds, const void* g) {
    __builtin_amdgcn_global_load_lds(
        (const __attribute__((address_space(1))) unsigned int*)g,
        (__attribute__((address_space(3))) unsigned int*)lds, 16, 0, 0);
}

// Level geometry (bc=4 fixed):
//   N-offsets: L0 @0 (4*4096), L1 @16384 (4*1024), L2 @20480 (4*256); NT=21504
#define NT_ALL   21504
#define OFF_L1   16384
#define OFF_L2   20480

// ---------------- fused prep: feat=0 | w fp32->bf16 | x -> xT bf16 ----------
__global__ __launch_bounds__(256) void prep_kernel(
    const float* __restrict__ x0, const float* __restrict__ x1,
    const float* __restrict__ x2,
    const float* __restrict__ wq, const float* __restrict__ wk,
    const float* __restrict__ wv,
    unsigned short* __restrict__ wb, unsigned short* __restrict__ xT,
    float* __restrict__ feat)
{
    __shared__ unsigned short tile[64][65];
    int bid = blockIdx.x;
    if (bid == 0) {
        for (int i = threadIdx.x; i < 2048; i += 256) feat[i] = 0.f;
        return;
    }
    bid -= 1;
    if (bid < 4608) {                        // weight convert
        int t = bid / 1536;
        int i = (bid % 1536) * 256 + threadIdx.x;
        const float* src = (t == 0) ? wq : (t == 1) ? wk : wv;
        wb[(size_t)t * 393216 + i] = f2bf(src[i]);
        return;
    }
    bid -= 4608;                             // transpose: 84 x 4 x 4
    int xb = bid % 84;
    int c0 = ((bid / 84) & 3) * 64;
    int b  = bid / 336;
    const float* xp; int tb, HW, lvl_off;
    if (xb < 64)      { xp = x0; tb = xb;      HW = 4096; lvl_off = 0;      }
    else if (xb < 80) { xp = x1; tb = xb - 64; HW = 1024; lvl_off = OFF_L1; }
    else              { xp = x2; tb = xb - 80; HW = 256;  lvl_off = OFF_L2; }
    int hw0 = tb * 64;
    xp += (size_t)b * 256 * HW;
    int tx = threadIdx.x & 63;
    int ty = threadIdx.x >> 6;               // 0..3
#pragma unroll
    for (int i = 0; i < 16; ++i) {
        int c = c0 + ty * 16 + i;
        tile[ty * 16 + i][tx] = f2bf(xp[(size_t)c * HW + hw0 + tx]);
    }
    __syncthreads();
    unsigned short* op = xT + ((size_t)lvl_off + (size_t)b * HW + hw0) * 256 + c0;
#pragma unroll
    for (int i = 0; i < 16; ++i) {
        int r = ty * 16 + i;                 // local hw row
        op[(size_t)r * 256 + tx] = tile[tx][r];
    }
}

// ---------------- QKV GEMM: qkv[z][o][n] = W[z,lvl(n)][o]·xT[n] + bias ------
// M=512, K=256, N=NT_ALL. 128x128 tile, BK=32, 4 waves, clean 2-phase
// double-buffer (m97 structure: stage-next, compute-cur, __syncthreads).
__global__ __launch_bounds__(256) void qkv_gemm_kernel(
    const unsigned short* __restrict__ wb,       // [3z][3lvl][512][256]
    const float* __restrict__ bq, const float* __restrict__ bk,
    const float* __restrict__ bv,                // each [3][512]
    const unsigned short* __restrict__ xT,       // [NT][256]
    unsigned short* __restrict__ qkv)            // [3z][512][NT]
{
    int bid = blockIdx.x;                        // 2016 = 8 * 252
    int swz = (bid & 7) * 252 + (bid >> 3);      // bijective XCD swizzle
    int nt  = swz / 12;                          // 0..167 n-tile
    int mz  = swz % 12;
    int z   = mz >> 2;
    int bm0 = (mz & 3) * 128;
    int bn0 = nt * 128;
    int lvl = (bn0 >= OFF_L2) ? 2 : (bn0 >= OFF_L1) ? 1 : 0;
    const unsigned short* Wm = wb + ((size_t)z * 3 + lvl) * 131072;
    const float* bias = ((z == 0) ? bq : (z == 1) ? bk : bv) + lvl * 512;
    unsigned short* out = qkv + (size_t)z * 512 * NT_ALL;

    __shared__ unsigned short smem[2][8192];     // per buf: A 4096, B 4096

    int tid  = threadIdx.x;
    int lane = tid & 63;
    int wid  = tid >> 6;                    // 0..3
    int wr   = wid >> 1, wc = wid & 1;
    int l15  = lane & 15;
    int kg   = lane >> 4;                   // 0..3

    f32x4 acc[4][4];
#pragma unroll
    for (int i = 0; i < 4; ++i)
#pragma unroll
        for (int j = 0; j < 4; ++j) acc[i][j] = (f32x4){0.f, 0.f, 0.f, 0.f};

    // staging rows for this lane (fragment order: slot = (mt*64+lane)*16B)
    int aRow0 = bm0 + (2 * wid)     * 16 + l15;
    int aRow1 = bm0 + (2 * wid + 1) * 16 + l15;
    int bRow0 = bn0 + (2 * wid)     * 16 + l15;
    int bRow1 = bn0 + (2 * wid + 1) * 16 + l15;
    int kbase = kg * 8;

    auto STAGE = [&](int t, int bufi) {
        int kk = t * 32 + kbase;
        unsigned short* As = smem[bufi];
        unsigned short* Bs = As + 4096;
        async16(As + (2 * wid)     * 512, Wm + (size_t)aRow0 * 256 + kk);
        async16(As + (2 * wid + 1) * 512, Wm + (size_t)aRow1 * 256 + kk);
        async16(Bs + (2 * wid)     * 512, xT + (size_t)bRow0 * 256 + kk);
        async16(Bs + (2 * wid + 1) * 512, xT + (size_t)bRow1 * 256 + kk);
    };

    STAGE(0, 0);
    __syncthreads();

    for (int it = 0; it < 8; ++it) {
        if (it < 7) STAGE(it + 1, (it + 1) & 1);
        const unsigned short* As = smem[it & 1];
        const unsigned short* Bs = As + 4096;
        bf16x8 af[4], bg[4];
#pragma unroll
        for (int mi = 0; mi < 4; ++mi)
            af[mi] = *reinterpret_cast<const bf16x8*>(As + ((wr * 4 + mi) * 64 + lane) * 8);
#pragma unroll
        for (int ni = 0; ni < 4; ++ni)
            bg[ni] = *reinterpret_cast<const bf16x8*>(Bs + ((wc * 4 + ni) * 64 + lane) * 8);
#pragma unroll
        for (int mi = 0; mi < 4; ++mi)
#pragma unroll
            for (int ni = 0; ni < 4; ++ni)
                acc[mi][ni] = __builtin_amdgcn_mfma_f32_16x16x32_bf16(
                    af[mi], bg[ni], acc[mi][ni], 0, 0, 0);
        __syncthreads();   // drains vmcnt/lgkm (compiler-inserted) + barrier
    }

#pragma unroll
    for (int mi = 0; mi < 4; ++mi) {
        int obase = bm0 + wr * 64 + mi * 16 + kg * 4;
#pragma unroll
        for (int ni = 0; ni < 4; ++ni) {
            int n = bn0 + wc * 64 + ni * 16 + l15;
#pragma unroll
            for (int r = 0; r < 4; ++r) {
                int o = obase + r;
                out[(size_t)o * NT_ALL + n] = f2bf(acc[mi][ni][r] + bias[o]);
            }
        }
    }
}

// ---------------- 3x3 local attention + relu + spatial-mean ----------------
// Per thread: 8 consecutive w positions. Lean math (no max-sub, exp2 with
// log2e folded into q, rel_h pre-added into k row). Edges fully vectorized:
// left/right neighbor u16x8 loads + per-lane cndmask (no exec-masked scalars).
__global__ __launch_bounds__(256) void attn_kernel(
    const unsigned short* __restrict__ qkv,      // [3z][512][NT]
    const float* __restrict__ bk, const float* __restrict__ bv,   // [3][512]
    const float* __restrict__ relh, const float* __restrict__ relw,// [3][256][3]
    float* __restrict__ feat)
{
    int xb = blockIdx.x;                 // 0..10: 8 L0 + 2 L1 + 1 L2(half)
    int c  = blockIdx.y;
    int lvl, lgW, lvl_off, hw_all;
    if (xb < 8)       { lvl = 0; lgW = 6; lvl_off = 0;      hw_all = xb * 2048 + threadIdx.x * 8; }
    else if (xb < 10) { lvl = 1; lgW = 5; lvl_off = OFF_L1; hw_all = (xb - 8) * 2048 + threadIdx.x * 8; }
    else              { lvl = 2; lgW = 4; lvl_off = OFF_L2; hw_all = threadIdx.x * 8; }
    int W = 1 << lgW, H = W, HW = W << lgW;
    bool active = hw_all < 4 * HW;       // only partial for L2 block
    int b  = hw_all >> (2 * lgW);
    int hw = hw_all & (HW - 1);
    int h = hw >> lgW, w0 = hw & (W - 1);

    size_t n0 = (size_t)lvl_off + hw_all;
    const unsigned short* qp = qkv + (size_t)c          * NT_ALL + n0;
    const unsigned short* kp = qkv + ((size_t)512 + c)  * NT_ALL + n0;
    const unsigned short* vp = qkv + ((size_t)1024 + c) * NT_ALL + n0;

    float bkc = bk[lvl * 512 + c], bvc = bv[lvl * 512 + c];
    bool ish = (c < 256);
    const float* rs = ish ? (relh + lvl * 768 + c * 3)
                          : (relw + lvl * 768 + (c - 256) * 3);
    float radd[3], rdc[3];
#pragma unroll
    for (int r = 0; r < 3; ++r) {
        float rv = rs[r];
        radd[r] = ish ? rv : 0.f;        // pre-added per stencil row
        rdc[r]  = ish ? 0.f : rv;        // fma offset per stencil col
    }

    float ysum = 0.f;
    if (active) {
        float krow[3][10], vf[3][10];
        u16x8 qv = *(const u16x8*)qp;
#pragma unroll
        for (int r = 0; r < 3; ++r) {
            int y = h + r - 1;
            float ra = radd[r];
            float kpad = bkc + ra;
            if ((unsigned)y < (unsigned)H) {
                int off = (r - 1) << lgW;     // dy*W (multiple of 8 -> aligned)
                u16x8 kv = *(const u16x8*)(kp + off);
                u16x8 vv = *(const u16x8*)(vp + off);
                u16x8 kl = *(const u16x8*)(kp + off - 8);
                u16x8 vl = *(const u16x8*)(vp + off - 8);
                u16x8 kr = *(const u16x8*)(kp + off + 8);
                u16x8 vr = *(const u16x8*)(vp + off + 8);
#pragma unroll
                for (int j = 0; j < 8; ++j) {
                    krow[r][j + 1] = bf2f(kv[j]) + ra;
                    vf[r][j + 1]   = bf2f(vv[j]);
                }
                bool hasL = (w0 > 0), hasR = (w0 + 8 < W);
                krow[r][0] = hasL ? bf2f(kl[7]) + ra : kpad;
                vf[r][0]   = hasL ? bf2f(vl[7])      : bvc;
                krow[r][9] = hasR ? bf2f(kr[0]) + ra : kpad;
                vf[r][9]   = hasR ? bf2f(vr[0])      : bvc;
            } else {
#pragma unroll
                for (int j = 0; j < 10; ++j) { krow[r][j] = kpad; vf[r][j] = bvc; }
            }
        }
#pragma unroll
        for (int j = 0; j < 8; ++j) {
            float qln = bf2f(qv[j]) * 1.4426950408889634f;   // q * log2(e)
            float pr0 = qln * rdc[0], pr1 = qln * rdc[1], pr2 = qln * rdc[2];
            float num = 0.f, den = 0.f;
#pragma unroll
            for (int r = 0; r < 3; ++r) {
                float p0 = exp2f(fmaf(qln, krow[r][j + 0], pr0));
                float p1 = exp2f(fmaf(qln, krow[r][j + 1], pr1));
                float p2 = exp2f(fmaf(qln, krow[r][j + 2], pr2));
                num = fmaf(p0, vf[r][j + 0], num);
                num = fmaf(p1, vf[r][j + 1], num);
                num = fmaf(p2, vf[r][j + 2], num);
                den += p0 + p1 + p2;
            }
            ysum += fmaxf(__fdividef(num, den), 0.f);
        }
        ysum *= (1.0f / HW);
    }
    // half-wave (32-lane) reduction: each half-wave covers 256 positions = one b
#pragma unroll
    for (int off = 16; off; off >>= 1) ysum += __shfl_down(ysum, off, 32);
    if (active && ((threadIdx.x & 31) == 0))
        atomicAdd(&feat[(size_t)b * 512 + c], ysum);
}

// ---------------- classifiers: grid-stride, feat held in registers ---------
__global__ __launch_bounds__(256) void logits_kernel(
    const float* __restrict__ feat,
    const float* __restrict__ ws, const float* __restrict__ bs,
    const float* __restrict__ wf, const float* __restrict__ bff,
    const float* __restrict__ wo, const float* __restrict__ bo,
    float* __restrict__ out)
{
    int lane = threadIdx.x & 63;
    int wid  = threadIdx.x >> 6;
    // feat fragment per lane: 4 batches x 2 halves x f32x4 = 32 floats
    f32x4 fr[4][2];
#pragma unroll
    for (int b = 0; b < 4; ++b) {
        fr[b][0] = *(const f32x4*)(feat + b * 512 + lane * 4);
        fr[b][1] = *(const f32x4*)(feat + b * 512 + 256 + lane * 4);
    }
    const int ROWS = 64500 + 489 + 140;
    for (int row = blockIdx.x * 4 + wid; row < ROWS; row += 8192) {
        const float* wm; float bias; size_t obase; int ostride;
        if (row < 64500) {
            wm = ws + (size_t)row * 512; bias = bs[row]; obase = (size_t)row; ostride = 64500;
        } else if (row < 64500 + 489) {
            int r = row - 64500;
            wm = wf + (size_t)r * 512; bias = bff[r]; obase = 258000 + (size_t)r; ostride = 489;
        } else {
            int r = row - 64989;
            wm = wo + (size_t)r * 512; bias = bo[r]; obase = 259956 + (size_t)r; ostride = 140;
        }
        f32x4 w1 = *(const f32x4*)(wm + lane * 4);
        f32x4 w2 = *(const f32x4*)(wm + 256 + lane * 4);
        float accs[4];
#pragma unroll
        for (int b = 0; b < 4; ++b) {
            f32x4 f1 = fr[b][0], f2 = fr[b][1];
            accs[b] = w1.x * f1.x + w1.y * f1.y + w1.z * f1.z + w1.w * f1.w
                    + w2.x * f2.x + w2.y * f2.y + w2.z * f2.z + w2.w * f2.w;
        }
#pragma unroll
        for (int off = 32; off; off >>= 1)
#pragma unroll
            for (int b = 0; b < 4; ++b) accs[b] += __shfl_down(accs[b], off, 64);
        if (lane == 0)
#pragma unroll
            for (int b = 0; b < 4; ++b) out[obase + (size_t)b * ostride] = accs[b] + bias;
    }
}

extern "C" void kernel_launch(void* const* d_in, const int* in_sizes, int n_in,
                              void* d_out, int out_size, void* d_ws, size_t ws_size,
                              hipStream_t stream)
{
    const float* x0  = (const float*)d_in[0];
    const float* x1  = (const float*)d_in[1];
    const float* x2  = (const float*)d_in[2];
    const float* wq  = (const float*)d_in[3];
    const float* bq  = (const float*)d_in[4];
    const float* wk  = (const float*)d_in[5];
    const float* bk  = (const float*)d_in[6];
    const float* wv  = (const float*)d_in[7];
    const float* bv  = (const float*)d_in[8];
    const float* relh = (const float*)d_in[9];
    const float* relw = (const float*)d_in[10];
    const float* ws  = (const float*)d_in[11];
    const float* bs  = (const float*)d_in[12];
    const float* wf  = (const float*)d_in[13];
    const float* bff = (const float*)d_in[14];
    const float* wo  = (const float*)d_in[15];
    const float* bo  = (const float*)d_in[16];
    float* out = (float*)d_out;

    char* wsb = (char*)d_ws;
    float* feat = (float*)wsb;                                   // 8 KB
    unsigned short* wb = (unsigned short*)(wsb + 8192);          // 2.36 MB
    unsigned short* xT = (unsigned short*)(wsb + 8192 + 2359296);          // 11 MB
    unsigned short* qkv = (unsigned short*)(wsb + 8192 + 2359296 + 11010048); // 66 MB

    prep_kernel<<<dim3(1 + 4608 + 1344), 256, 0, stream>>>(
        x0, x1, x2, wq, wk, wv, wb, xT, feat);
    qkv_gemm_kernel<<<dim3(2016), 256, 0, stream>>>(
        wb, bq, bk, bv, xT, qkv);
    attn_kernel<<<dim3(11, 512, 1), 256, 0, stream>>>(
        qkv, bk, bv, relh, relw, feat);
    logits_kernel<<<dim3(2048), 256, 0, stream>>>(feat, ws, bs, wf, bff, wo, bo, out);
}